// Round 15
// baseline (232.927 us; speedup 1.0000x reference)
//
#include <hip/hip_runtime.h>

#define N_NODES 50000
#define N_EDGES 600000
#define N_GRAPHS 128
#define DIM 128
#define NLAYERS 3
#define NOUT 10
#define ELLW 48       // max degree slots (deg~Pois(12), P(>=48)~1e-21; clamped)
#define LSTRIDE 136   // LDS row stride in bf16 elems (272B = 17*16B: aligned, 2-way max)
#define ZROW N_NODES  // dummy all-zero feature row for branch-free gather padding
#define GTILE 64      // rows per gather block
#define NGTILES 782   // ceil(50000/64), even

typedef unsigned short u16;
typedef unsigned int u32;
typedef __attribute__((ext_vector_type(8))) short bf16x8;
typedef __attribute__((ext_vector_type(4))) float f32x4;

__device__ __forceinline__ float bf2f(u16 v) {
    unsigned u = ((unsigned)v) << 16;
    return __builtin_bit_cast(float, u);
}
__device__ __forceinline__ u16 f2bf(float f) {  // round-to-nearest-even
    unsigned u = __builtin_bit_cast(unsigned, f);
    u = u + 0x7fffu + ((u >> 16) & 1u);
    return (u16)(u >> 16);
}

// ---------------------------------------------------------------------------
// tiny: zero deg (incl. pad) + pooled
__global__ void zero_small(int* __restrict__ deg, float* __restrict__ pooled) {
    int i = blockIdx.x * blockDim.x + threadIdx.x;
    if (i < N_NODES + 64) deg[i] = 0;
    if (i < N_GRAPHS * DIM) pooled[i] = 0.f;
}

// ELL build: direct scatter (50000 counters -> low atomic depth)
__global__ void prep_ell(int* __restrict__ deg, u16* __restrict__ ell,
                         const int* __restrict__ srcs, const int* __restrict__ dsts) {
    int i = blockIdx.x * blockDim.x + threadIdx.x;
    if (i >= N_EDGES) return;
    int d = dsts[i];
    int slot = atomicAdd(&deg[d], 1);
    if (slot < ELLW) ell[(size_t)d * ELLW + slot] = (u16)srcs[i];
}

// conversions: x->bf16 + W pre-swizzle + zero pad rows
__global__ void prep_cvt(u16* __restrict__ xb, u16* __restrict__ bufA, u16* __restrict__ bufB,
                         const float* __restrict__ x, u16* __restrict__ Wswz,
                         const float* __restrict__ convW1, const float* __restrict__ convW2) {
    int i = blockIdx.x * blockDim.x + threadIdx.x;
    if (i < DIM) {  // zero the ZROW pad row of all three activation buffers
        xb[(size_t)ZROW * DIM + i] = 0;
        bufA[(size_t)ZROW * DIM + i] = 0;
        bufB[(size_t)ZROW * DIM + i] = 0;
    }
    if (i < 6 * 16384) {
        int j = i & 7, lane = (i >> 3) & 63, cb = (i >> 9) & 7, kc = (i >> 12) & 3, w = i >> 14;
        int k = kc * 32 + ((lane >> 4) << 3) + j;
        int c = (cb << 4) + (lane & 15);
        const float* W = (w < 3) ? (convW1 + (size_t)w * 16384) : (convW2 + (size_t)(w - 3) * 16384);
        Wswz[i] = f2bf(W[k * DIM + c]);
    }
    if (i < N_NODES * DIM / 4) {
        float4 v = ((const float4*)x)[i];
        ushort4 o;
        o.x = f2bf(v.x); o.y = f2bf(v.y); o.z = f2bf(v.z); o.w = f2bf(v.w);
        ((ushort4*)xb)[i] = o;
    }
}

// ---------------------------------------------------------------------------
// Column-split gather: agg[n][cg-slice] = x[n][slice] + sum_nb x[nb][slice].
// Grid 3128 = 391*8; b -> xcd=b&7, cg=xcd&3, tile=(b>>3)*2+(xcd>>2).
// With round-robin block->XCD dispatch, each XCD touches ONE 32-col slice of x
// (50000*64B = 3.2 MB -> fits 4 MB per-XCD L2): random reads become L2 hits.
// Block: 64 rows x 32 cols; lane=(row-quarter, col-pair); no LDS, no barriers.
__global__ __launch_bounds__(256) void gather_cg(u16* __restrict__ agg,
                                                 const u16* __restrict__ x,
                                                 const int* __restrict__ deg,
                                                 const u16* __restrict__ ell) {
    const int b = blockIdx.x;
    const int xcd = b & 7;
    const int cg = xcd & 3;
    const int tile = ((b >> 3) << 1) + (xcd >> 2);  // 0..781
    const int row0 = tile * GTILE;
    const int tid = threadIdx.x;
    const int wv = tid >> 6;
    const int lane = tid & 63;
    const int rsub = lane >> 4;                       // 0..3
    const int coff = (cg << 5) + ((lane & 15) << 1);  // col byte-pair in slice

#pragma unroll
    for (int g = 0; g < 4; ++g) {
        const int row = row0 + (wv << 4) + (g << 2) + rsub;
        const int grow = min(row, ZROW);  // pad rows -> ZROW (deg 0, zero feats)
        const int len = min(deg[grow], ELLW);
        const u16* ep = ell + (size_t)grow * ELLW;
        ushort2 self = *(const ushort2*)(x + (size_t)grow * DIM + coff);
        float ax = bf2f(self.x), ay = bf2f(self.y);
        for (int j = 0; __any(j < len); j += 4) {
            ushort4 e = *(const ushort4*)(ep + j);  // 8B-aligned (96B rows)
            int i0 = (j + 0 < len) ? (int)e.x : ZROW;
            int i1 = (j + 1 < len) ? (int)e.y : ZROW;
            int i2 = (j + 2 < len) ? (int)e.z : ZROW;
            int i3 = (j + 3 < len) ? (int)e.w : ZROW;
            ushort2 v0 = *(const ushort2*)(x + (size_t)i0 * DIM + coff);
            ushort2 v1 = *(const ushort2*)(x + (size_t)i1 * DIM + coff);
            ushort2 v2 = *(const ushort2*)(x + (size_t)i2 * DIM + coff);
            ushort2 v3 = *(const ushort2*)(x + (size_t)i3 * DIM + coff);
            ax += (bf2f(v0.x) + bf2f(v1.x)) + (bf2f(v2.x) + bf2f(v3.x));
            ay += (bf2f(v0.y) + bf2f(v1.y)) + (bf2f(v2.y) + bf2f(v3.y));
        }
        if (row < N_NODES) {
            ushort2 o;
            o.x = f2bf(ax);
            o.y = f2bf(ay);
            *(ushort2*)(agg + (size_t)row * DIM + coff) = o;
        }
    }
}

// ---------------------------------------------------------------------------
// Fused 2-layer MLP: out = relu(W2·relu(BN(W1·agg + b1)) + b2), bf16 in/out.
// Block 256 = 4 waves x 16 wave-private rows (no barriers). A-frags from
// global agg (16B/lane, coalesced); W frags from L2-resident swizzled global.
// POOL=1: per-wave per-graph column sums -> pooled (batch sorted).
template <int POOL>
__global__ __launch_bounds__(256) void mlp_pool(
    u16* __restrict__ out, const u16* __restrict__ agg,
    const u16* __restrict__ W1f, const u16* __restrict__ W2f,
    const float* __restrict__ b1, const float* __restrict__ g1,
    const float* __restrict__ bt1, const float* __restrict__ b2,
    const int* __restrict__ batch, float* __restrict__ pooled) {
    __shared__ u16 lds[4][16 * LSTRIDE];  // 17408 B
    const int wv = threadIdx.x >> 6;
    const int lane = threadIdx.x & 63;
    const int row0 = blockIdx.x * 64 + wv * 16;
    u16* H = lds[wv];

    const float inv = rsqrtf(1.f + 1e-5f);
    const int col0 = lane & 15;
    const int rbl = (lane >> 4) << 2;
    const int fragoff = (lane & 15) * LSTRIDE + ((lane >> 4) << 3);

    // ---- GEMM1 + BN + ReLU -> H (LDS) ----
    {
        const int arow = min(row0 + (lane & 15), N_NODES - 1);
        const u16* ap = agg + (size_t)arow * DIM + ((lane >> 4) << 3);
        f32x4 acc[8];
#pragma unroll
        for (int cb = 0; cb < 8; ++cb) acc[cb] = (f32x4){0.f, 0.f, 0.f, 0.f};
#pragma unroll
        for (int kc = 0; kc < 4; ++kc) {
            bf16x8 a = *(const bf16x8*)(ap + kc * 32);
#pragma unroll
            for (int cb = 0; cb < 8; ++cb) {
                bf16x8 bb = *(const bf16x8*)(W1f + ((((kc << 3) + cb) << 6 | lane) << 3));
                acc[cb] = __builtin_amdgcn_mfma_f32_16x16x32_bf16(a, bb, acc[cb], 0, 0, 0);
            }
        }
#pragma unroll
        for (int cb = 0; cb < 8; ++cb) {
            const int c = (cb << 4) + col0;
            const float bias = b1[c];
            const float sg = inv * g1[c];
            const float st = bt1[c];
#pragma unroll
            for (int q = 0; q < 4; ++q) {
                float v = (acc[cb][q] + bias) * sg + st;
                H[(rbl + q) * LSTRIDE + c] = f2bf(fmaxf(v, 0.f));
            }
        }
    }

    // ---- GEMM2 + bias + ReLU -> H (reused as staging) ----
    {
        f32x4 acc[8];
#pragma unroll
        for (int cb = 0; cb < 8; ++cb) acc[cb] = (f32x4){0.f, 0.f, 0.f, 0.f};
#pragma unroll
        for (int kc = 0; kc < 4; ++kc) {
            bf16x8 a = *(const bf16x8*)&H[fragoff + kc * 32];
#pragma unroll
            for (int cb = 0; cb < 8; ++cb) {
                bf16x8 bb = *(const bf16x8*)(W2f + ((((kc << 3) + cb) << 6 | lane) << 3));
                acc[cb] = __builtin_amdgcn_mfma_f32_16x16x32_bf16(a, bb, acc[cb], 0, 0, 0);
            }
        }
#pragma unroll
        for (int cb = 0; cb < 8; ++cb) {
            const int c = (cb << 4) + col0;
            const float bias = b2[c];
#pragma unroll
            for (int q = 0; q < 4; ++q) {
                float v = acc[cb][q] + bias;
                H[(rbl + q) * LSTRIDE + c] = f2bf(fmaxf(v, 0.f));
            }
        }
    }

    if (!POOL) {
        // ---- coalesced copy-out (2 rows / pass, 8B / lane) ----
#pragma unroll
        for (int it = 0; it < 8; ++it) {
            const int r = it * 2 + (lane >> 5);
            const int grow = row0 + r;
            const int m = lane & 31;
            uint2 v = *(const uint2*)&H[r * LSTRIDE + m * 4];
            if (grow < N_NODES) *(uint2*)(out + (size_t)grow * DIM + m * 4) = v;
        }
    } else {
        // ---- per-wave pool: lane owns cols {2l,2l+1}; flush on graph change ----
        const int c0 = lane * 2;
        float sx = 0.f, sy = 0.f;
        int curg = batch[min(row0, N_NODES - 1)];
        for (int r = 0; r < 16; ++r) {
            const int row = row0 + r;
            const int g = batch[min(row, N_NODES - 1)];
            if (g != curg) {
                atomicAdd(&pooled[(size_t)curg * DIM + c0], sx);
                atomicAdd(&pooled[(size_t)curg * DIM + c0 + 1], sy);
                sx = 0.f; sy = 0.f; curg = g;
            }
            if (row < N_NODES) {
                sx += bf2f(H[r * LSTRIDE + c0]);
                sy += bf2f(H[r * LSTRIDE + c0 + 1]);
            }
        }
        atomicAdd(&pooled[(size_t)curg * DIM + c0], sx);
        atomicAdd(&pooled[(size_t)curg * DIM + c0 + 1], sy);
    }
}

// ---------------------------------------------------------------------------
// final MLP per graph
__global__ __launch_bounds__(128) void tail_mlp(float* __restrict__ out,
                                                const float* __restrict__ pooled,
                                                const float* __restrict__ mW1,
                                                const float* __restrict__ mb1,
                                                const float* __restrict__ mg,
                                                const float* __restrict__ mbt,
                                                const float* __restrict__ mW2,
                                                const float* __restrict__ mb2) {
    const int g = blockIdx.x;
    const int c = threadIdx.x;
    __shared__ float pl[DIM];
    __shared__ float hd[DIM];
    pl[c] = pooled[(size_t)g * DIM + c];
    __syncthreads();

    float s = 0.f;
#pragma unroll 4
    for (int k = 0; k < DIM; ++k) s += pl[k] * mW1[k * DIM + c];
    const float inv = rsqrtf(1.f + 1e-5f);
    s = (s + mb1[c]) * (inv * mg[c]) + mbt[c];
    hd[c] = fmaxf(s, 0.f);
    __syncthreads();

    if (c < NOUT) {
        float o = 0.f;
#pragma unroll 4
        for (int k = 0; k < DIM; ++k) o += hd[k] * mW2[k * NOUT + c];
        out[g * NOUT + c] = o + mb2[c];
    }
}

// ---------------------------------------------------------------------------
extern "C" void kernel_launch(void* const* d_in, const int* in_sizes, int n_in,
                              void* d_out, int out_size, void* d_ws, size_t ws_size,
                              hipStream_t stream) {
    const float* x      = (const float*)d_in[0];
    const int*   ei     = (const int*)d_in[1];
    const int*   batch  = (const int*)d_in[2];
    const float* convW1 = (const float*)d_in[3];
    const float* convb1 = (const float*)d_in[4];
    const float* convg  = (const float*)d_in[5];
    const float* convbt = (const float*)d_in[6];
    const float* convW2 = (const float*)d_in[7];
    const float* convb2 = (const float*)d_in[8];
    const float* mW1    = (const float*)d_in[9];
    const float* mb1    = (const float*)d_in[10];
    const float* mg     = (const float*)d_in[11];
    const float* mbt    = (const float*)d_in[12];
    const float* mW2    = (const float*)d_in[13];
    const float* mb2    = (const float*)d_in[14];
    float* out = (float*)d_out;

    const int* srcs = ei;
    const int* dsts = ei + N_EDGES;

    // workspace layout (x-buffers have N_NODES+1 rows: ZROW pad)
    const size_t NFP = (size_t)(N_NODES + 1) * DIM;
    u16* xb0  = (u16*)d_ws;       // bf16 input features (+ zero pad row)
    u16* bufA = xb0 + NFP;
    u16* bufB = bufA + NFP;
    u16* aggbuf = bufB + NFP;     // N_NODES*DIM (reads clamped, writes guarded)
    u16* Wswz = aggbuf + (size_t)N_NODES * DIM;  // 6*16384 bf16
    float* pooled = (float*)(Wswz + 6 * 16384);
    int* deg = (int*)(pooled + N_GRAPHS * DIM);   // N_NODES + 64 (pad)
    u16* ell = (u16*)(deg + N_NODES + 64);        // (N_NODES+128) * ELLW u16

    // ---- init + ELL scatter + conversions ----
    zero_small<<<(N_NODES + 64 + 255) / 256, 256, 0, stream>>>(deg, pooled);
    prep_ell<<<(N_EDGES + 255) / 256, 256, 0, stream>>>(deg, ell, srcs, dsts);
    prep_cvt<<<(N_NODES * DIM / 4 + 255) / 256, 256, 0, stream>>>(
        xb0, bufA, bufB, x, Wswz, convW1, convW2);

    // ---- 3 GIN layers: col-split gather + fused MLP ----
    const int gatherBlocks = (NGTILES / 2) * 8;       // 3128
    const int mlpBlocks    = (N_NODES + 63) / 64;     // 782
    const u16* cur = xb0;
    u16* nxt = bufA;
    for (int l = 0; l < NLAYERS; ++l) {
        gather_cg<<<gatherBlocks, 256, 0, stream>>>(aggbuf, cur, deg, ell);
        if (l < NLAYERS - 1) {
            mlp_pool<0><<<mlpBlocks, 256, 0, stream>>>(
                nxt, aggbuf, Wswz + (size_t)l * 16384, Wswz + (size_t)(3 + l) * 16384,
                convb1 + l * DIM, convg + l * DIM, convbt + l * DIM, convb2 + l * DIM,
                batch, pooled);
        } else {
            mlp_pool<1><<<mlpBlocks, 256, 0, stream>>>(
                nxt, aggbuf, Wswz + (size_t)l * 16384, Wswz + (size_t)(3 + l) * 16384,
                convb1 + l * DIM, convg + l * DIM, convbt + l * DIM, convb2 + l * DIM,
                batch, pooled);
        }
        cur = nxt;
        nxt = (nxt == bufA) ? bufB : bufA;
    }

    // ---- final MLP ----
    tail_mlp<<<N_GRAPHS, 128, 0, stream>>>(out, pooled, mW1, mb1, mg, mbt, mW2, mb2);
}

// Round 16
// 153.888 us; speedup vs baseline: 1.5136x; 1.5136x over previous
//
#include <hip/hip_runtime.h>

#define N_NODES 50000
#define N_EDGES 600000
#define N_GRAPHS 128
#define DIM 128
#define NLAYERS 3
#define NOUT 10
#define ELLW 48       // max degree slots (deg~Pois(12), P(>=48)~1e-21; clamped)
#define LSTRIDE 136   // LDS row stride in bf16 elems (272B = 17*16B: aligned, 2-way max)
#define ZROW N_NODES  // dummy all-zero feature row for branch-free gather padding
#define DEGS 16       // deg padding stride: 1 counter per 64B line (atomic de-contention)

typedef unsigned short u16;
typedef unsigned int u32;
typedef __attribute__((ext_vector_type(8))) short bf16x8;
typedef __attribute__((ext_vector_type(4))) float f32x4;

__device__ __forceinline__ float bf2f(u16 v) {
    unsigned u = ((unsigned)v) << 16;
    return __builtin_bit_cast(float, u);
}
__device__ __forceinline__ u16 f2bf(float f) {  // round-to-nearest-even
    unsigned u = __builtin_bit_cast(unsigned, f);
    u = u + 0x7fffu + ((u >> 16) & 1u);
    return (u16)(u >> 16);
}

// ---------------------------------------------------------------------------
// zero padded deg (coalesced 3.2MB memset) + pooled
__global__ void zero_small(int* __restrict__ degp, float* __restrict__ pooled) {
    int i = blockIdx.x * blockDim.x + threadIdx.x;
    if (i < N_NODES * DEGS) degp[i] = 0;
    if (i < N_GRAPHS * DIM) pooled[i] = 0.f;
}

// merged prep: ELL scatter (padded counters) + x->bf16 + W swizzle + pad rows
__global__ void prep_all(int* __restrict__ degp, u16* __restrict__ ell,
                         const int* __restrict__ srcs, const int* __restrict__ dsts,
                         u16* __restrict__ xb, u16* __restrict__ bufA, u16* __restrict__ bufB,
                         const float* __restrict__ x, u16* __restrict__ Wswz,
                         const float* __restrict__ convW1, const float* __restrict__ convW2) {
    int i = blockIdx.x * blockDim.x + threadIdx.x;
    if (i < N_EDGES) {
        int d = dsts[i];
        int slot = atomicAdd(&degp[(size_t)d * DEGS], 1);  // 12 atomics/line vs 192
        if (slot < ELLW) ell[(size_t)d * ELLW + slot] = (u16)srcs[i];
    }
    if (i < DIM) {  // zero the ZROW pad row of all three activation buffers
        xb[(size_t)ZROW * DIM + i] = 0;
        bufA[(size_t)ZROW * DIM + i] = 0;
        bufB[(size_t)ZROW * DIM + i] = 0;
    }
    if (i < 6 * 16384) {
        int j = i & 7, lane = (i >> 3) & 63, cb = (i >> 9) & 7, kc = (i >> 12) & 3, w = i >> 14;
        int k = kc * 32 + ((lane >> 4) << 3) + j;
        int c = (cb << 4) + (lane & 15);
        const float* W = (w < 3) ? (convW1 + (size_t)w * 16384) : (convW2 + (size_t)(w - 3) * 16384);
        Wswz[i] = f2bf(W[k * DIM + c]);
    }
    if (i < N_NODES * DIM / 4) {
        float4 v = ((const float4*)x)[i];
        ushort4 o;
        o.x = f2bf(v.x); o.y = f2bf(v.y); o.z = f2bf(v.z); o.w = f2bf(v.w);
        ((ushort4*)xb)[i] = o;
    }
}

// ---------------------------------------------------------------------------
// Fused GIN layer: out = relu(MLP2(relu(BN(MLP1(x + ELL-gather(x))))))
// 256 threads = 4 waves; tile 16 rows (50000 = 3125*16, no guards).
// Gather: 4 rows x 4 neighbors interleaved -> 16 outstanding row-loads/round
// (branch-free via ZROW). POOL=1: per-graph column sums -> pooled.
template <int POOL>
__global__ __launch_bounds__(256) void layer_fused(
    u16* __restrict__ out, const u16* __restrict__ x,
    const int* __restrict__ degp, const u16* __restrict__ ell,
    const u16* __restrict__ W1f, const u16* __restrict__ W2f,
    const float* __restrict__ b1, const float* __restrict__ g1,
    const float* __restrict__ bt1, const float* __restrict__ b2,
    const int* __restrict__ batch, float* __restrict__ pooled) {
    __shared__ u16 A[16 * LSTRIDE];  // 4352 B
    __shared__ u16 H[16 * LSTRIDE];  // 4352 B
    __shared__ int gb[16];
    const int tid = threadIdx.x;
    const int wv = tid >> 6;
    const int lane = tid & 63;
    const int row0 = blockIdx.x * 16;

    if (POOL && tid < 16) gb[tid] = batch[row0 + tid];

    // ---- phase 1: interleaved gather (wave wv -> rows wv*4..wv*4+3) ----
    const size_t coff = (size_t)lane * 2;
    {
        const int r0 = wv << 2;
        int len[4];
        const u16* ep[4];
        float ax[4], ay[4];
#pragma unroll
        for (int r = 0; r < 4; ++r) {
            const int grow = row0 + r0 + r;
            len[r] = min(degp[(size_t)grow * DEGS], ELLW);
            ep[r] = ell + (size_t)grow * ELLW;
            ushort2 self = *(const ushort2*)(x + (size_t)grow * DIM + coff);
            ax[r] = bf2f(self.x);
            ay[r] = bf2f(self.y);
        }
        const int maxlen = max(max(len[0], len[1]), max(len[2], len[3]));
        for (int j = 0; j < maxlen; j += 4) {
            int id[4][4];
#pragma unroll
            for (int r = 0; r < 4; ++r) {
                ushort4 e = *(const ushort4*)(ep[r] + j);  // 8B-aligned (96B rows)
                id[r][0] = (j + 0 < len[r]) ? (int)e.x : ZROW;
                id[r][1] = (j + 1 < len[r]) ? (int)e.y : ZROW;
                id[r][2] = (j + 2 < len[r]) ? (int)e.z : ZROW;
                id[r][3] = (j + 3 < len[r]) ? (int)e.w : ZROW;
            }
#pragma unroll
            for (int r = 0; r < 4; ++r) {
                float px = 0.f, py = 0.f;
#pragma unroll
                for (int t = 0; t < 4; ++t) {
                    ushort2 v = *(const ushort2*)(x + (size_t)id[r][t] * DIM + coff);
                    px += bf2f(v.x);
                    py += bf2f(v.y);
                }
                ax[r] += px;
                ay[r] += py;
            }
        }
#pragma unroll
        for (int r = 0; r < 4; ++r) {
            ushort2 o;
            o.x = f2bf(ax[r]);
            o.y = f2bf(ay[r]);
            *(ushort2*)&A[(r0 + r) * LSTRIDE + lane * 2] = o;
        }
    }
    __syncthreads();

    // ---- MFMA setup: wave wv owns col-blocks {2wv, 2wv+1} ----
    const float inv = rsqrtf(1.f + 1e-5f);
    const int col0 = lane & 15;
    const int rbl = (lane >> 4) << 2;  // C/D local row base
    const int fragoff = (lane & 15) * LSTRIDE + ((lane >> 4) << 3);

    // ---- phase 2: GEMM1 + BN + ReLU -> H ----
    {
        f32x4 acc[2];
        acc[0] = (f32x4){0.f, 0.f, 0.f, 0.f};
        acc[1] = (f32x4){0.f, 0.f, 0.f, 0.f};
#pragma unroll
        for (int kc = 0; kc < 4; ++kc) {
            bf16x8 a = *(const bf16x8*)&A[fragoff + kc * 32];
#pragma unroll
            for (int m = 0; m < 2; ++m) {
                const int cb = (wv << 1) + m;
                bf16x8 bb = *(const bf16x8*)(W1f + ((((kc << 3) + cb) << 6 | lane) << 3));
                acc[m] = __builtin_amdgcn_mfma_f32_16x16x32_bf16(a, bb, acc[m], 0, 0, 0);
            }
        }
#pragma unroll
        for (int m = 0; m < 2; ++m) {
            const int c = (((wv << 1) + m) << 4) + col0;
            const float bias = b1[c];
            const float sg = inv * g1[c];
            const float st = bt1[c];
#pragma unroll
            for (int q = 0; q < 4; ++q) {
                float v = (acc[m][q] + bias) * sg + st;
                H[(rbl + q) * LSTRIDE + c] = f2bf(fmaxf(v, 0.f));
            }
        }
    }
    __syncthreads();

    // ---- phase 3: GEMM2 + bias + ReLU -> A (dead; reuse as staging) ----
    {
        f32x4 acc[2];
        acc[0] = (f32x4){0.f, 0.f, 0.f, 0.f};
        acc[1] = (f32x4){0.f, 0.f, 0.f, 0.f};
#pragma unroll
        for (int kc = 0; kc < 4; ++kc) {
            bf16x8 a = *(const bf16x8*)&H[fragoff + kc * 32];
#pragma unroll
            for (int m = 0; m < 2; ++m) {
                const int cb = (wv << 1) + m;
                bf16x8 bb = *(const bf16x8*)(W2f + ((((kc << 3) + cb) << 6 | lane) << 3));
                acc[m] = __builtin_amdgcn_mfma_f32_16x16x32_bf16(a, bb, acc[m], 0, 0, 0);
            }
        }
#pragma unroll
        for (int m = 0; m < 2; ++m) {
            const int c = (((wv << 1) + m) << 4) + col0;
            const float bias = b2[c];
#pragma unroll
            for (int q = 0; q < 4; ++q) {
                float v = acc[m][q] + bias;
                A[(rbl + q) * LSTRIDE + c] = f2bf(fmaxf(v, 0.f));
            }
        }
    }
    __syncthreads();

    if (!POOL) {
        // ---- phase 4: coalesced copy-out (256 thr x 16B = full tile) ----
        const int r = tid >> 4;       // 0..15
        const int seg = tid & 15;     // 16B column segment
        uint4 v = *(const uint4*)&A[r * LSTRIDE + seg * 8];
        *(uint4*)(out + (size_t)(row0 + r) * DIM + seg * 8) = v;
    } else {
        // ---- phase 4': per-graph column sums -> pooled (atomicAdd) ----
        const int c = tid & 127;
        const int rbeg = (tid >> 7) << 3;  // 0 or 8
        float acc = 0.f;
        int curg = gb[rbeg];
#pragma unroll
        for (int r = 0; r < 8; ++r) {
            const int g = gb[rbeg + r];
            if (g != curg) {
                atomicAdd(&pooled[(size_t)curg * DIM + c], acc);
                acc = 0.f;
                curg = g;
            }
            acc += bf2f(A[(rbeg + r) * LSTRIDE + c]);
        }
        atomicAdd(&pooled[(size_t)curg * DIM + c], acc);
    }
}

// ---------------------------------------------------------------------------
// final MLP per graph
__global__ __launch_bounds__(128) void tail_mlp(float* __restrict__ out,
                                                const float* __restrict__ pooled,
                                                const float* __restrict__ mW1,
                                                const float* __restrict__ mb1,
                                                const float* __restrict__ mg,
                                                const float* __restrict__ mbt,
                                                const float* __restrict__ mW2,
                                                const float* __restrict__ mb2) {
    const int g = blockIdx.x;
    const int c = threadIdx.x;
    __shared__ float pl[DIM];
    __shared__ float hd[DIM];
    pl[c] = pooled[(size_t)g * DIM + c];
    __syncthreads();

    float s = 0.f;
#pragma unroll 4
    for (int k = 0; k < DIM; ++k) s += pl[k] * mW1[k * DIM + c];
    const float inv = rsqrtf(1.f + 1e-5f);
    s = (s + mb1[c]) * (inv * mg[c]) + mbt[c];
    hd[c] = fmaxf(s, 0.f);
    __syncthreads();

    if (c < NOUT) {
        float o = 0.f;
#pragma unroll 4
        for (int k = 0; k < DIM; ++k) o += hd[k] * mW2[k * NOUT + c];
        out[g * NOUT + c] = o + mb2[c];
    }
}

// ---------------------------------------------------------------------------
extern "C" void kernel_launch(void* const* d_in, const int* in_sizes, int n_in,
                              void* d_out, int out_size, void* d_ws, size_t ws_size,
                              hipStream_t stream) {
    const float* x      = (const float*)d_in[0];
    const int*   ei     = (const int*)d_in[1];
    const int*   batch  = (const int*)d_in[2];
    const float* convW1 = (const float*)d_in[3];
    const float* convb1 = (const float*)d_in[4];
    const float* convg  = (const float*)d_in[5];
    const float* convbt = (const float*)d_in[6];
    const float* convW2 = (const float*)d_in[7];
    const float* convb2 = (const float*)d_in[8];
    const float* mW1    = (const float*)d_in[9];
    const float* mb1    = (const float*)d_in[10];
    const float* mg     = (const float*)d_in[11];
    const float* mbt    = (const float*)d_in[12];
    const float* mW2    = (const float*)d_in[13];
    const float* mb2    = (const float*)d_in[14];
    float* out = (float*)d_out;

    const int* srcs = ei;
    const int* dsts = ei + N_EDGES;

    // workspace layout (activation buffers have N_NODES+1 rows: ZROW pad)
    const size_t NFP = (size_t)(N_NODES + 1) * DIM;
    u16* xb0  = (u16*)d_ws;       // bf16 input features (+ zero pad row)
    u16* bufA = xb0 + NFP;
    u16* bufB = bufA + NFP;
    u16* Wswz = bufB + NFP;       // 6*16384 bf16
    float* pooled = (float*)(Wswz + 6 * 16384);
    int* degp = (int*)(pooled + N_GRAPHS * DIM);  // N_NODES*DEGS ints (padded)
    u16* ell = (u16*)(degp + (size_t)N_NODES * DEGS);  // N_NODES*ELLW u16

    // ---- init + merged prep (ELL scatter + cvt + wprep + pad rows) ----
    zero_small<<<(N_NODES * DEGS + 255) / 256, 256, 0, stream>>>(degp, pooled);
    prep_all<<<(N_NODES * DIM / 4 + 255) / 256, 256, 0, stream>>>(
        degp, ell, srcs, dsts, xb0, bufA, bufB, x, Wswz, convW1, convW2);

    // ---- 3 fused GIN layers (3125 blocks x 16 rows, exact) ----
    const int layerBlocks = N_NODES / 16;
    layer_fused<0><<<layerBlocks, 256, 0, stream>>>(
        bufA, xb0, degp, ell, Wswz, Wswz + (size_t)3 * 16384,
        convb1, convg, convbt, convb2, batch, pooled);
    layer_fused<0><<<layerBlocks, 256, 0, stream>>>(
        bufB, bufA, degp, ell, Wswz + (size_t)1 * 16384, Wswz + (size_t)4 * 16384,
        convb1 + DIM, convg + DIM, convbt + DIM, convb2 + DIM, batch, pooled);
    layer_fused<1><<<layerBlocks, 256, 0, stream>>>(
        bufA /*unused*/, bufB, degp, ell, Wswz + (size_t)2 * 16384, Wswz + (size_t)5 * 16384,
        convb1 + 2 * DIM, convg + 2 * DIM, convbt + 2 * DIM, convb2 + 2 * DIM, batch, pooled);

    // ---- final MLP ----
    tail_mlp<<<N_GRAPHS, 128, 0, stream>>>(out, pooled, mW1, mb1, mg, mbt, mW2, mb2);
}